// Round 15
// baseline (31.906 us; speedup 1.0000x reference)
//
#include <hip/hip_runtime.h>

// Gaussian-splat heatmap as a per-image MFMA GEMM — SINGLE pass with bf16 LDS
// staging of the unnormalized heat (vs R11's two-pass recompute, 24.26us).
//   heat[y][x] = sum_p Rmat[y][p] * CmatT[x][p]   (M=N=200 padded to 224, K=64)
//   Rmat[y][p]  = k1n[y-ys_p] if 0<=y-ys_p<ky_p else 0  (top-left-slice quirk)
//   CmatT[x][p] = k1n[x-xs_p] if 0<=x-xs_p<kx_p else 0
// bf16 LDS rows of 128 B, XOR-swizzled byte ^= ((row&7)<<4) (G4/T2).
// mfma_f32_32x32x16_bf16; A-frag: lane l -> row l&31, k=8*(l>>5)+j;
// C/D: col=lane&31, row=(reg&3)+8*(reg>>2)+4*(lane>>5)   [m74/m101]
//
// Structure: build -> ONE GEMM sweep (accs -> bf16 -> stage[200][200] in LDS,
// f32 max tracked in regs) -> barrier + max reduce -> drain: all 512 threads
// stream the stage as contiguous float4 pairs (bf16->f32 * scale). Perfectly
// coalesced full-line writes: no partial-line eviction, no RFO, no pass-2
// MFMA recompute. LDS 137.4 KB -> 1 block/CU, 512 blocks = 2 pipelined rounds
// (round-2 build/GEMM overlaps round-1 drain).
// Precision: staging adds one bf16 rounding (rel <= 2^-9) -> absmax ~1e-2
// worst case vs threshold 2e-2.
// Falsifier: >=24us -> occupancy loss dominates; revert to R11.

#define NT 64
#define TDIM 224
#define NTL 7
#define BLK 512

typedef short bf16x8 __attribute__((ext_vector_type(8)));
typedef float f32x16 __attribute__((ext_vector_type(16)));

// f32 -> bf16 round-to-nearest-even
static __device__ inline unsigned short f2bf(float f) {
    unsigned int u = __float_as_uint(f);
    u = (u + 0x7FFFu + ((u >> 16) & 1u)) >> 16;
    return (unsigned short)u;
}

struct __align__(16) SMem {
    unsigned short Rm[TDIM][64];     // 28,672 B, swizzled (rows = y)
    unsigned short Cm[TDIM][64];     // 28,672 B, swizzled (rows = x)
    unsigned short stage[200][200];  // 80,000 B unnormalized heat, bf16
    float k1f[37];
    float wmax[NTL];
};

__global__ __launch_bounds__(BLK) void heatmap_kernel(const float* __restrict__ x_t,
                                                      float* __restrict__ out) {
    __shared__ SMem s;
    const int tid  = threadIdx.x;
    const int lane = tid & 63;
    const int wv   = tid >> 6;      // 0..7 (wave 7 idle in GEMM; helps build+drain)
    const int b    = blockIdx.x;

    // --- (1) zero-fill Rm+Cm with b128 writes: 57,344 B = 3584 x 16 B ---
    {
        uint4 z = {0u, 0u, 0u, 0u};
        uint4* base = (uint4*)s.Rm;
        #pragma unroll
        for (int i = 0; i < 7; ++i) base[tid + BLK * i] = z;
    }
    // --- (2) f32 normalized 1-D gaussian table ---
    if (tid < 37) {
        float sum = 0.0f, mine = 0.0f;
        #pragma unroll
        for (int i = 0; i < 37; ++i) {
            float r = (float)(i - 18);
            float v = expf(-(r * r) * (1.0f / 18.0f));   // sigma=3 -> 2*sigma^2=18
            sum += v;
            if (i == tid) mine = v;
        }
        s.k1f[tid] = mine / sum;
    }
    __syncthreads();

    // --- (3) sparse build: task = (point p, matrix R/C), 4 threads x 9 rows ---
    {
        const int p   = (tid >> 2) & 63;    // point
        const int isC = tid >> 8;           // 0: Rm (rows=y), 1: Cm (rows=x)
        const int j   = tid & 3;            // 9-row slice
        const float2 xy = *(const float2*)(x_t + (size_t)b * 128 + 2 * p);
        // replicates reference exactly
        const bool valid = (xy.x == xy.x) && (xy.y == xy.y);
        const int xp = (int)(xy.x * 2.0f);            // trunc == astype(int32), x>=0
        const int yp = 200 - (int)(xy.y * 2.0f);
        const int xs = min(max(xp - 18, 0), 164);
        const int ys = min(max(yp - 18, 0), 164);
        const int kx = valid ? (min(max(xp + 18, 0), 200) - xs) : 0;   // <= 36
        const int ky = valid ? (min(max(yp + 18, 0), 200) - ys) : 0;
        const int start = isC ? xs : ys;
        const int len   = isC ? kx : ky;
        char* dst = isC ? (char*)s.Cm : (char*)s.Rm;
        #pragma unroll
        for (int i = 0; i < 9; ++i) {
            const int rel = j * 9 + i;                // 0..35
            if (rel < len) {
                const int row = start + rel;          // <= 199
                const int off = (2 * p) ^ ((row & 7) << 4);
                *(unsigned short*)(dst + row * 128 + off) = f2bf(s.k1f[rel]);
            }
        }
    }
    __syncthreads();

    const int swl = (lane & 7) << 4;    // swizzle term (rows = t*32+(lane&31))

    // --- single GEMM pass: accs -> bf16 stage; f32 max in registers ---
    float gmax = 0.0f;
    if (wv < NTL) {
        bf16x8 A[4];
        const char* ab = (const char*)s.Rm + (wv * 32 + (lane & 31)) * 128;
        #pragma unroll
        for (int m = 0; m < 4; ++m)
            A[m] = *(const bf16x8*)(ab + ((16 * (2 * m + (lane >> 5))) ^ swl));

        const int gcolbase = lane & 31;
        const int rowoff   = wv * 32 + 4 * (lane >> 5);
        for (int tx = 0; tx < NTL; ++tx) {
            const char* bb = (const char*)s.Cm + (tx * 32 + (lane & 31)) * 128;
            f32x16 acc;
            #pragma unroll
            for (int r = 0; r < 16; ++r) acc[r] = 0.0f;
            #pragma unroll
            for (int m = 0; m < 4; ++m) {
                bf16x8 B = *(const bf16x8*)(bb + ((16 * (2 * m + (lane >> 5))) ^ swl));
                acc = __builtin_amdgcn_mfma_f32_32x32x16_bf16(A[m], B, acc, 0, 0, 0);
            }
            const int gcol = tx * 32 + gcolbase;
            #pragma unroll
            for (int r = 0; r < 16; ++r) {
                const int grow = rowoff + (r & 3) + 8 * (r >> 2);
                gmax = fmaxf(gmax, acc[r]);           // pad rows/cols are 0, harmless
                if (grow < 200 && gcol < 200)
                    s.stage[grow][gcol] = f2bf(acc[r]);
            }
        }
    }
    #pragma unroll
    for (int off = 32; off > 0; off >>= 1) gmax = fmaxf(gmax, __shfl_xor(gmax, off));
    if (wv < NTL && lane == 0) s.wmax[wv] = gmax;
    __syncthreads();                                  // stage + wmax complete
    float mm = s.wmax[0];
    #pragma unroll
    for (int w = 1; w < NTL; ++w) mm = fmaxf(mm, s.wmax[w]);
    const float scale = 1.0f / (mm + 1e-10f);

    // --- drain: contiguous float4-pair stores, bf16->f32 * scale ---
    {
        const unsigned short* sp = &s.stage[0][0];
        float* ob = out + (size_t)b * (200 * 200);
        for (int i = tid; i < 5000; i += BLK) {       // 5000 x 16 B = 80,000 B
            uint4 v = *(const uint4*)(sp + 8 * i);
            float4 lo, hi;
            lo.x = __uint_as_float(v.x << 16) * scale;
            lo.y = __uint_as_float(v.x & 0xFFFF0000u) * scale;
            lo.z = __uint_as_float(v.y << 16) * scale;
            lo.w = __uint_as_float(v.y & 0xFFFF0000u) * scale;
            hi.x = __uint_as_float(v.z << 16) * scale;
            hi.y = __uint_as_float(v.z & 0xFFFF0000u) * scale;
            hi.z = __uint_as_float(v.w << 16) * scale;
            hi.w = __uint_as_float(v.w & 0xFFFF0000u) * scale;
            *(float4*)(ob + 8 * i)     = lo;
            *(float4*)(ob + 8 * i + 4) = hi;
        }
    }
}

extern "C" void kernel_launch(void* const* d_in, const int* in_sizes, int n_in,
                              void* d_out, int out_size, void* d_ws, size_t ws_size,
                              hipStream_t stream) {
    const float* x_t = (const float*)d_in[0];
    float* out = (float*)d_out;
    const int B = in_sizes[0] / (NT * 2);   // 512
    heatmap_kernel<<<B, BLK, 0, stream>>>(x_t, out);
}

// Round 16
// 24.560 us; speedup vs baseline: 1.2991x; 1.2991x over previous
//
#include <hip/hip_runtime.h>

// Gaussian-splat heatmap as a per-image MFMA GEMM — SINGLE pass, 16-row strip
// accumulators held in registers, drain overlapped across 2 images per block.
//   heat[y][x] = sum_p Rmat[y][p] * CmatT[x][p]   (M=N=200 padded to 224, K=64)
//   Rmat[y][p]  = k1n[y-ys_p] if 0<=y-ys_p<ky_p else 0  (top-left-slice quirk)
//   CmatT[x][p] = k1n[x-xs_p] if 0<=x-xs_p<kx_p else 0
// bf16 LDS rows of 128 B, XOR-swizzled byte ^= ((row&7)<<4) (G4/T2).
// mfma_f32_16x16x32_bf16 (layouts verified by R13's pass):
//   A: row=lane&15, k=8*(lane>>4)+j (+32 for the second K-half)
//   C/D: col=lane&15, row=4*(lane>>4)+reg
//
// Model recalibration (R15: 2 serial rounds @16us => compute ~5us/image;
// R10 bounds write-amp <= ~4us): R11's 24.26 = 2x5 compute (lockstep, HBM
// idle) + 12.5 drain. Fix both: single pass (halves GEMM work) with 52-VGPR
// strip accs (13 x f32x4), and 2 images/block so image-1's LDS-only
// build+GEMM overlaps image-0's fire-and-forget store drain.
// Grid 256 (1 block/CU), block 896 = 14 waves (strip w of 13 useful;
// launch_bounds(896,4) caps VGPR at 128 so all 14 waves are resident).

#define NT 64
#define TDIM 224
#define BLK 896

typedef short bf16x8 __attribute__((ext_vector_type(8)));
typedef float f32x4  __attribute__((ext_vector_type(4)));

// f32 -> bf16 round-to-nearest-even
static __device__ inline unsigned short f2bf(float f) {
    unsigned int u = __float_as_uint(f);
    u = (u + 0x7FFFu + ((u >> 16) & 1u)) >> 16;
    return (unsigned short)u;
}

struct __align__(16) SMem {
    unsigned short Rm[TDIM][64];   // 28,672 B, swizzled (rows = y)
    unsigned short Cm[TDIM][64];   // 28,672 B, swizzled (rows = x)
    float k1f[37];                 // f32 normalized 1-D gaussian (persistent)
    float wmax[14];
};

__global__ __launch_bounds__(BLK, 4) void heatmap_kernel(const float* __restrict__ x_t,
                                                         float* __restrict__ out) {
    __shared__ SMem s;
    const int tid  = threadIdx.x;
    const int lane = tid & 63;
    const int wv   = tid >> 6;      // 0..13
    const int swl  = (lane & 7) << 4;

    // --- normalized 1-D gaussian table (once; persists across both images) ---
    if (tid < 37) {
        float sum = 0.0f, mine = 0.0f;
        #pragma unroll
        for (int i = 0; i < 37; ++i) {
            float r = (float)(i - 18);
            float v = expf(-(r * r) * (1.0f / 18.0f));   // sigma=3 -> 2*sigma^2=18
            sum += v;
            if (i == tid) mine = v;
        }
        s.k1f[tid] = mine / sum;
    }

    for (int img = 0; img < 2; ++img) {
        const int b = 2 * blockIdx.x + img;

        // --- zero-fill Rm+Cm: 3584 x 16 B (exactly 4 per thread) ---
        __syncthreads();                   // img0: k1f ready; img1: prev reads done
        {
            uint4 z = {0u, 0u, 0u, 0u};
            uint4* base = (uint4*)s.Rm;
            #pragma unroll
            for (int i = 0; i < 4; ++i) base[tid + BLK * i] = z;
        }
        __syncthreads();

        // --- sparse build: 128 tasks (point x {R,C}) x 7 threads x 6 rows ---
        {
            const int isC = tid >= 448;
            const int t2  = tid - (isC ? 448 : 0);
            const int p   = t2 / 7;          // 0..63
            const int j   = t2 - 7 * p;      // 0..6
            const float2 xy = *(const float2*)(x_t + (size_t)b * 128 + 2 * p);
            // replicates reference exactly
            const bool valid = (xy.x == xy.x) && (xy.y == xy.y);
            const int xp = (int)(xy.x * 2.0f);        // trunc == astype(int32), x>=0
            const int yp = 200 - (int)(xy.y * 2.0f);
            const int xs = min(max(xp - 18, 0), 164);
            const int ys = min(max(yp - 18, 0), 164);
            const int kx = valid ? (min(max(xp + 18, 0), 200) - xs) : 0;   // <= 36
            const int ky = valid ? (min(max(yp + 18, 0), 200) - ys) : 0;
            const int start = isC ? xs : ys;
            const int len   = isC ? kx : ky;
            char* dst = isC ? (char*)s.Cm : (char*)s.Rm;
            #pragma unroll
            for (int i = 0; i < 6; ++i) {
                const int rel = j * 6 + i;            // 0..41 (covers 0..35)
                if (rel < len) {
                    const int row = start + rel;      // <= 199
                    const int off = (2 * p) ^ ((row & 7) << 4);
                    *(unsigned short*)(dst + row * 128 + off) = f2bf(s.k1f[rel]);
                }
            }
        }
        __syncthreads();

        // --- single GEMM pass: wave wv owns 16-row strip [16*wv, 16*wv+16) ---
        f32x4 acc[13];
        float gmax = 0.0f;
        if (wv < 13) {
            bf16x8 A0, A1;
            {
                const char* ab = (const char*)s.Rm + (16 * wv + (lane & 15)) * 128;
                A0 = *(const bf16x8*)(ab + ((16 * (lane >> 4)) ^ swl));
                A1 = *(const bf16x8*)(ab + ((16 * (lane >> 4) + 64) ^ swl));
            }
            #pragma unroll
            for (int t = 0; t < 13; ++t) {
                #pragma unroll
                for (int r = 0; r < 4; ++r) acc[t][r] = 0.0f;
            }
            #pragma unroll
            for (int t = 0; t < 13; ++t) {
                const char* bb = (const char*)s.Cm + (16 * t + (lane & 15)) * 128;
                bf16x8 B0 = *(const bf16x8*)(bb + ((16 * (lane >> 4)) ^ swl));
                bf16x8 B1 = *(const bf16x8*)(bb + ((16 * (lane >> 4) + 64) ^ swl));
                acc[t] = __builtin_amdgcn_mfma_f32_16x16x32_bf16(A0, B0, acc[t], 0, 0, 0);
                acc[t] = __builtin_amdgcn_mfma_f32_16x16x32_bf16(A1, B1, acc[t], 0, 0, 0);
            }
            // pad rows/cols (>=200) hold exact zeros -> unguarded max is safe
            #pragma unroll
            for (int t = 0; t < 13; ++t) {
                #pragma unroll
                for (int r = 0; r < 4; ++r) gmax = fmaxf(gmax, acc[t][r]);
            }
        }
        #pragma unroll
        for (int off = 32; off > 0; off >>= 1) gmax = fmaxf(gmax, __shfl_xor(gmax, off));
        if (lane == 0) s.wmax[wv] = gmax;
        __syncthreads();
        float mm = s.wmax[0];
        #pragma unroll
        for (int w = 1; w < 14; ++w) mm = fmaxf(mm, s.wmax[w]);
        const float scale = 1.0f / (mm + 1e-10f);

        // --- burst stores from registers (fire-and-forget; drain overlaps the
        //     next image's LDS-only build+GEMM) ---
        if (wv < 13) {
            float* ob = out + (size_t)b * (200 * 200);
            const int rbase = 16 * wv + 4 * (lane >> 4);
            const int cbase = lane & 15;
            #pragma unroll
            for (int t = 0; t < 13; ++t) {
                const int gcol = 16 * t + cbase;
                #pragma unroll
                for (int r = 0; r < 4; ++r) {
                    const int grow = rbase + r;
                    if (grow < 200 && gcol < 200)
                        ob[(size_t)grow * 200 + gcol] = acc[t][r] * scale;
                }
            }
        }
    }
}

extern "C" void kernel_launch(void* const* d_in, const int* in_sizes, int n_in,
                              void* d_out, int out_size, void* d_ws, size_t ws_size,
                              hipStream_t stream) {
    const float* x_t = (const float*)d_in[0];
    float* out = (float*)d_out;
    const int B = in_sizes[0] / (NT * 2);   // 512
    heatmap_kernel<<<B / 2, BLK, 0, stream>>>(x_t, out);
}

// Round 17
// 23.328 us; speedup vs baseline: 1.3677x; 1.0528x over previous
//
#include <hip/hip_runtime.h>

// Gaussian-splat heatmap as a per-image MFMA GEMM — amp-free stores:
// per-wave PRIVATE LDS stage + contiguous 128B-aligned drain, 2 blocks/CU.
//   heat[y][x] = sum_p Rmat[y][p] * CmatT[x][p]   (M=N=200 padded to 224, K=64)
//   Rmat[y][p]  = k1n[y-ys_p] if 0<=y-ys_p<ky_p else 0  (top-left-slice quirk)
//   CmatT[x][p] = k1n[x-xs_p] if 0<=x-xs_p<kx_p else 0
// bf16 LDS rows of 128 B, XOR-swizzled byte ^= ((row&7)<<4) (G4/T2).
// mfma_f32_16x16x32_bf16 (verified R13/R16): A row=lane&15, k=8*(lane>>4)+j
// (+32 second half); C/D col=lane&15 (=x), row=4*(lane>>4)+reg (=y).
//
// R16 proved the wall isn't compute (half work = same 24.5us). Model: 80MB x
// ~2 write-amp / 6.5TB/s = 24.6us = the wall. Amp cause: 800B rows make all
// MFMA-native store segments line-misaligned; partial lines evict from L2.
// Fix: wave computes a 16-row strip (13 x f32x4 accs), stages scaled bf16 in
// its PRIVATE 6.4KB LDS area (no barriers), drains its strip as contiguous
// 128B-aligned uint4 stores (16 rows x 800B = one 12.8KB span, full lines
// only). Draining waves stall on vmcnt; the other 15 resident waves compute.
// 2 blk/CU via sequential single-buffer build: build Rm -> cache ALL A-frags
// in regs -> rebuild same 28.7KB buffer as Cm. LDS ~80.1KB <= 81.9KB.
// Stage adds one bf16 rounding: absmax <= ~1.2e-2 (threshold 2e-2).
// Falsifier: >=24us -> amp wasn't the wall -> structural plateau.

#define NT 64
#define TDIM 224
#define BLK 512

typedef short bf16x8 __attribute__((ext_vector_type(8)));
typedef float f32x4  __attribute__((ext_vector_type(4)));

// f32 -> bf16 round-to-nearest-even
static __device__ inline unsigned short f2bf(float f) {
    unsigned int u = __float_as_uint(f);
    u = (u + 0x7FFFu + ((u >> 16) & 1u)) >> 16;
    return (unsigned short)u;
}

struct __align__(16) SMem {
    unsigned short M[TDIM][64];        // 28,672 B: Rm first, then rebuilt as Cm
    unsigned short stg[8][16][200];    // 51,200 B: per-wave private stage
    float k1f[37];
    float wmax[8];
};

__global__ __launch_bounds__(BLK, 4) void heatmap_kernel(const float* __restrict__ x_t,
                                                         float* __restrict__ out) {
    __shared__ SMem s;
    const int tid  = threadIdx.x;
    const int lane = tid & 63;
    const int wv   = tid >> 6;          // 0..7
    const int b    = blockIdx.x;
    const int swl  = (lane & 7) << 4;

    // --- zero M + k1f table ---
    {
        uint4 z = {0u, 0u, 0u, 0u};
        uint4* base = (uint4*)s.M;
        #pragma unroll
        for (int i = 0; i < 4; ++i) {
            const int idx = tid + BLK * i;
            if (idx < 1792) base[idx] = z;
        }
    }
    if (tid < 37) {
        float sum = 0.0f, mine = 0.0f;
        #pragma unroll
        for (int i = 0; i < 37; ++i) {
            float r = (float)(i - 18);
            float v = expf(-(r * r) * (1.0f / 18.0f));   // sigma=3 -> 2*sigma^2=18
            sum += v;
            if (i == tid) mine = v;
        }
        s.k1f[tid] = mine / sum;
    }
    __syncthreads();

    // --- per-point meta: 8 threads per point (replicates reference exactly) ---
    const int p = tid >> 3, j = tid & 7;
    const float2 xy = *(const float2*)(x_t + (size_t)b * 128 + 2 * p);
    const bool valid = (xy.x == xy.x) && (xy.y == xy.y);
    const int xp = (int)(xy.x * 2.0f);                 // trunc == astype(int32), x>=0
    const int yp = 200 - (int)(xy.y * 2.0f);
    const int xs = min(max(xp - 18, 0), 164);
    const int ys = min(max(yp - 18, 0), 164);
    const int kx = valid ? (min(max(xp + 18, 0), 200) - xs) : 0;   // <= 36
    const int ky = valid ? (min(max(yp + 18, 0), 200) - ys) : 0;

    // --- build Rm (rows = y) ---
    #pragma unroll
    for (int i = 0; i < 5; ++i) {
        const int rel = j * 5 + i;                     // 0..39 covers 0..35
        if (rel < ky) {
            const int row = ys + rel;
            *(unsigned short*)((char*)s.M + row * 128 + ((2 * p) ^ ((row & 7) << 4)))
                = f2bf(s.k1f[rel]);
        }
    }
    __syncthreads();

    // --- cache A-frags for this wave's strips (s1 = wv, s2 = wv+8 if < 13) ---
    const int s1 = wv, s2 = wv + 8;
    bf16x8 A10, A11, A20, A21;
    {
        const char* ab = (const char*)s.M + (16 * s1 + (lane & 15)) * 128;
        A10 = *(const bf16x8*)(ab + ((16 * (lane >> 4)) ^ swl));
        A11 = *(const bf16x8*)(ab + ((16 * (lane >> 4) + 64) ^ swl));
    }
    if (s2 < 13) {
        const char* ab = (const char*)s.M + (16 * s2 + (lane & 15)) * 128;
        A20 = *(const bf16x8*)(ab + ((16 * (lane >> 4)) ^ swl));
        A21 = *(const bf16x8*)(ab + ((16 * (lane >> 4) + 64) ^ swl));
    } else { A20 = A10; A21 = A11; }
    __syncthreads();                                   // all A-frag reads done

    // --- re-zero M, rebuild as Cm (rows = x) ---
    {
        uint4 z = {0u, 0u, 0u, 0u};
        uint4* base = (uint4*)s.M;
        #pragma unroll
        for (int i = 0; i < 4; ++i) {
            const int idx = tid + BLK * i;
            if (idx < 1792) base[idx] = z;
        }
    }
    __syncthreads();
    #pragma unroll
    for (int i = 0; i < 5; ++i) {
        const int rel = j * 5 + i;
        if (rel < kx) {
            const int row = xs + rel;
            *(unsigned short*)((char*)s.M + row * 128 + ((2 * p) ^ ((row & 7) << 4)))
                = f2bf(s.k1f[rel]);
        }
    }
    __syncthreads();

    // --- strip compute helper: 13 col-tiles, K=64 as two 16x16x32 MFMAs ---
    auto compute_strip = [&](bf16x8 A0, bf16x8 A1, f32x4* acc) {
        #pragma unroll
        for (int t = 0; t < 13; ++t) {
            acc[t][0] = 0.0f; acc[t][1] = 0.0f; acc[t][2] = 0.0f; acc[t][3] = 0.0f;
        }
        #pragma unroll
        for (int t = 0; t < 13; ++t) {
            const char* bb = (const char*)s.M + (16 * t + (lane & 15)) * 128;
            bf16x8 B0 = *(const bf16x8*)(bb + ((16 * (lane >> 4)) ^ swl));
            bf16x8 B1 = *(const bf16x8*)(bb + ((16 * (lane >> 4) + 64) ^ swl));
            acc[t] = __builtin_amdgcn_mfma_f32_16x16x32_bf16(A0, B0, acc[t], 0, 0, 0);
            acc[t] = __builtin_amdgcn_mfma_f32_16x16x32_bf16(A1, B1, acc[t], 0, 0, 0);
        }
    };

    // --- pass 1: max (pad rows/cols >=200 are exact zeros -> unguarded max ok) ---
    float gmax = 0.0f;
    {
        f32x4 acc[13];
        compute_strip(A10, A11, acc);
        #pragma unroll
        for (int t = 0; t < 13; ++t)
            #pragma unroll
            for (int r = 0; r < 4; ++r) gmax = fmaxf(gmax, acc[t][r]);
        if (s2 < 13) {
            compute_strip(A20, A21, acc);
            #pragma unroll
            for (int t = 0; t < 13; ++t)
                #pragma unroll
                for (int r = 0; r < 4; ++r) gmax = fmaxf(gmax, acc[t][r]);
        }
    }
    #pragma unroll
    for (int off = 32; off > 0; off >>= 1) gmax = fmaxf(gmax, __shfl_xor(gmax, off));
    if (lane == 0) s.wmax[wv] = gmax;
    __syncthreads();
    float mm = s.wmax[0];
    #pragma unroll
    for (int w = 1; w < 8; ++w) mm = fmaxf(mm, s.wmax[w]);
    const float scale = 1.0f / (mm + 1e-10f);

    // --- pass 2: recompute strip -> private stage (scaled bf16) -> contiguous
    //     128B-aligned drain. No barriers; draining waves overlap computing ones.
    float* ob = out + (size_t)b * (200 * 200);
    unsigned short* st = &s.stg[wv][0][0];
    auto do_strip = [&](int ss, bf16x8 A0, bf16x8 A1) {
        f32x4 acc[13];
        compute_strip(A0, A1, acc);
        const int r0l = 4 * (lane >> 4), c0l = lane & 15;
        #pragma unroll
        for (int t = 0; t < 13; ++t) {
            const int col = 16 * t + c0l;
            if (col < 200) {                      // t=12 cols 200..207 would OOB
                #pragma unroll
                for (int r = 0; r < 4; ++r)
                    st[(r0l + r) * 200 + col] = f2bf(acc[t][r] * scale);
            }
        }
        __threadfence_block();                    // order stage writes before reads
        const int nrow = min(16, 200 - 16 * ss);  // 16, or 8 for strip 12
        float* obs = ob + (size_t)(16 * ss) * 200;
        for (int i = lane; i < nrow * 50; i += 64) {
            uint2 v = *(const uint2*)(st + 4 * i);
            float4 o;
            o.x = __uint_as_float(v.x << 16);
            o.y = __uint_as_float(v.x & 0xFFFF0000u);
            o.z = __uint_as_float(v.y << 16);
            o.w = __uint_as_float(v.y & 0xFFFF0000u);
            *(float4*)(obs + 4 * i) = o;          // contiguous, 128B-aligned, full lines
        }
    };
    do_strip(s1, A10, A11);
    if (s2 < 13) do_strip(s2, A20, A21);
}

extern "C" void kernel_launch(void* const* d_in, const int* in_sizes, int n_in,
                              void* d_out, int out_size, void* d_ws, size_t ws_size,
                              hipStream_t stream) {
    const float* x_t = (const float*)d_in[0];
    float* out = (float*)d_out;
    const int B = in_sizes[0] / (NT * 2);   // 512
    heatmap_kernel<<<B, BLK, 0, stream>>>(x_t, out);
}